// Round 1
// baseline (5753.447 us; speedup 1.0000x reference)
//
#include <hip/hip_runtime.h>
#include <cstdint>
#include <cstddef>

#define NN 100000
#define NE 1600000
#define F  128
#define NPAD 100352  // NN rounded up, keeps segments 16B-aligned

// ---------------- degree + norm ----------------
__global__ void deg_kernel(const int* __restrict__ src, const int* __restrict__ dst,
                           int* __restrict__ deg_out, int* __restrict__ deg_in, int nE) {
    int e = blockIdx.x * blockDim.x + threadIdx.x;
    if (e < nE) {
        atomicAdd(&deg_out[src[e]], 1);
        atomicAdd(&deg_in[dst[e]], 1);
    }
}

__global__ void norm_kernel(const int* __restrict__ deg_out, const int* __restrict__ deg_in,
                            float* __restrict__ norm_src, float* __restrict__ norm_dst, int nN) {
    int n = blockIdx.x * blockDim.x + threadIdx.x;
    if (n < nN) {
        norm_src[n] = rsqrtf((float)max(deg_out[n], 1));
        norm_dst[n] = rsqrtf((float)max(deg_in[n], 1));
    }
}

// ---------------- fused GEMM: out[n][:] = (pre(in[n][:]) @ W) * norm_src[n] ----------------
// pre (layer2 only): t[k] = relu(in[n][k]*norm_dst[n] + b_pre[k])
template<bool PRE>
__global__ __launch_bounds__(256, 2)
void gemm_kernel(const float* __restrict__ in, const float* __restrict__ W,
                 const float* __restrict__ b_pre, const float* __restrict__ norm_dst,
                 const float* __restrict__ norm_src, float* __restrict__ out) {
    __shared__ __align__(16) float Ws[F * F];      // [k][c]  64 KB
    __shared__ __align__(16) float xs[32][F];      // 16 KB row tile

    const int tid = threadIdx.x;
    // stage W once per block
    for (int i = tid * 4; i < F * F; i += 256 * 4) {
        *(float4*)&Ws[i] = *(const float4*)&W[i];
    }

    const int l  = tid & 63;
    const int w  = tid >> 6;        // wave 0..3
    const int cg = l & 31;          // col group -> cols 4*cg..4*cg+3
    const int rg = l >> 5;          // row sub-group
    const int c0 = cg * 4;

    const int nTiles = NN / 32;     // 3125 exact
    for (int tile = blockIdx.x; tile < nTiles; tile += gridDim.x) {
        const int row0 = tile * 32;
        __syncthreads();            // also covers Ws on first iteration
        // stage 32x128 tile: 1024 float4s over 256 threads
        for (int i = tid; i < 32 * 32; i += 256) {
            const int r  = i >> 5;
            const int k4 = (i & 31) * 4;
            float4 v = *(const float4*)&in[(size_t)(row0 + r) * F + k4];
            if constexpr (PRE) {
                const float nd = norm_dst[row0 + r];
                const float4 bb = *(const float4*)&b_pre[k4];
                v.x = fmaxf(v.x * nd + bb.x, 0.f);
                v.y = fmaxf(v.y * nd + bb.y, 0.f);
                v.z = fmaxf(v.z * nd + bb.z, 0.f);
                v.w = fmaxf(v.w * nd + bb.w, 0.f);
            }
            *(float4*)&xs[r][k4] = v;
        }
        __syncthreads();

        const int r0 = 8 * w + 4 * rg;   // 4 rows per lane
        float4 a0 = {0,0,0,0}, a1 = {0,0,0,0}, a2 = {0,0,0,0}, a3 = {0,0,0,0};
        #pragma unroll 8
        for (int k = 0; k < F; ++k) {
            const float4 wv = *(const float4*)&Ws[k * F + c0];
            const float x0 = xs[r0 + 0][k];
            const float x1 = xs[r0 + 1][k];
            const float x2 = xs[r0 + 2][k];
            const float x3 = xs[r0 + 3][k];
            a0.x += x0 * wv.x; a0.y += x0 * wv.y; a0.z += x0 * wv.z; a0.w += x0 * wv.w;
            a1.x += x1 * wv.x; a1.y += x1 * wv.y; a1.z += x1 * wv.z; a1.w += x1 * wv.w;
            a2.x += x2 * wv.x; a2.y += x2 * wv.y; a2.z += x2 * wv.z; a2.w += x2 * wv.w;
            a3.x += x3 * wv.x; a3.y += x3 * wv.y; a3.z += x3 * wv.z; a3.w += x3 * wv.w;
        }
        {
            const float ns0 = norm_src[row0 + r0 + 0];
            const float ns1 = norm_src[row0 + r0 + 1];
            const float ns2 = norm_src[row0 + r0 + 2];
            const float ns3 = norm_src[row0 + r0 + 3];
            float4 o;
            o.x = a0.x*ns0; o.y = a0.y*ns0; o.z = a0.z*ns0; o.w = a0.w*ns0;
            *(float4*)&out[(size_t)(row0 + r0 + 0) * F + c0] = o;
            o.x = a1.x*ns1; o.y = a1.y*ns1; o.z = a1.z*ns1; o.w = a1.w*ns1;
            *(float4*)&out[(size_t)(row0 + r0 + 1) * F + c0] = o;
            o.x = a2.x*ns2; o.y = a2.y*ns2; o.z = a2.z*ns2; o.w = a2.w*ns2;
            *(float4*)&out[(size_t)(row0 + r0 + 2) * F + c0] = o;
            o.x = a3.x*ns3; o.y = a3.y*ns3; o.z = a3.z*ns3; o.w = a3.w*ns3;
            *(float4*)&out[(size_t)(row0 + r0 + 3) * F + c0] = o;
        }
    }
}

// ---------------- edge scatter: agg[dst] += hs[src]  (32 lanes x float4 per edge) ----------------
__global__ void scatter_kernel(const float* __restrict__ hs, const int* __restrict__ src,
                               const int* __restrict__ dst, float* __restrict__ agg, int nE) {
    const int idx = blockIdx.x * blockDim.x + threadIdx.x;
    const int e  = idx >> 5;
    const int f4 = (idx & 31) * 4;
    if (e < nE) {
        const int s = src[e];
        const int d = dst[e];
        const float4 v = *(const float4*)&hs[(size_t)s * F + f4];
        float* p = &agg[(size_t)d * F + f4];
        atomicAdd(p + 0, v.x);
        atomicAdd(p + 1, v.y);
        atomicAdd(p + 2, v.z);
        atomicAdd(p + 3, v.w);
    }
}

// ---------------- final node embeddings -> link-head partials a[n], c[n] ----------------
// h2[n][k] = agg[n][k]*norm_dst[n] + b2[k];  a[n] = h2·Wp[:128];  c[n] = h2·Wp[128:]
__global__ void node_kernel(const float* __restrict__ agg, const float* __restrict__ norm_dst,
                            const float* __restrict__ b2, const float* __restrict__ Wp,
                            float* __restrict__ a, float* __restrict__ c, int nN) {
    const int gid = blockIdx.x * blockDim.x + threadIdx.x;
    const int n = gid >> 6;          // one wave per node
    const int l = gid & 63;
    if (n < nN) {
        const float nd = norm_dst[n];
        const float2 v  = *(const float2*)&agg[(size_t)n * F + 2 * l];
        const float2 bb = *(const float2*)&b2[2 * l];
        const float h0 = v.x * nd + bb.x;
        const float h1 = v.y * nd + bb.y;
        const float2 wa = *(const float2*)&Wp[2 * l];
        const float2 wc = *(const float2*)&Wp[F + 2 * l];
        float pa = h0 * wa.x + h1 * wa.y;
        float pc = h0 * wc.x + h1 * wc.y;
        #pragma unroll
        for (int off = 32; off > 0; off >>= 1) {
            pa += __shfl_xor(pa, off);
            pc += __shfl_xor(pc, off);
        }
        if (l == 0) { a[n] = pa; c[n] = pc; }
    }
}

// ---------------- edge scores ----------------
__global__ void score_kernel(const float* __restrict__ a, const float* __restrict__ c,
                             const int* __restrict__ src, const int* __restrict__ dst,
                             const float* __restrict__ bp, float* __restrict__ out, int nE) {
    const int e = blockIdx.x * blockDim.x + threadIdx.x;
    if (e < nE) {
        const float z = a[src[e]] + c[dst[e]] + bp[0];
        out[e] = 1.f / (1.f + expf(-z));
    }
}

extern "C" void kernel_launch(void* const* d_in, const int* in_sizes, int n_in,
                              void* d_out, int out_size, void* d_ws, size_t ws_size,
                              hipStream_t stream) {
    const float* x  = (const float*)d_in[0];
    const float* W1 = (const float*)d_in[1];
    const float* b1 = (const float*)d_in[2];
    const float* W2 = (const float*)d_in[3];
    const float* b2 = (const float*)d_in[4];
    const float* Wp = (const float*)d_in[5];
    const float* bp = (const float*)d_in[6];
    const int*   src = (const int*)d_in[7];
    const int*   dst = (const int*)d_in[8];
    float* out = (float*)d_out;

    float* ws       = (float*)d_ws;
    float* norm_src = ws;                       // NPAD
    float* norm_dst = norm_src + NPAD;          // NPAD
    float* bufA     = norm_dst + NPAD;          // NPAD (deg_out, later a[])
    float* bufC     = bufA + NPAD;              // NPAD (deg_in, later c[])
    float* hs       = bufC + NPAD;              // NN*F
    float* agg      = hs + (size_t)NN * F;      // NN*F

    // degrees -> norms
    hipMemsetAsync(bufA, 0, 2 * NPAD * sizeof(float), stream);
    deg_kernel<<<(NE + 255) / 256, 256, 0, stream>>>(src, dst, (int*)bufA, (int*)bufC, NE);
    norm_kernel<<<(NN + 255) / 256, 256, 0, stream>>>((int*)bufA, (int*)bufC, norm_src, norm_dst, NN);

    // layer 1: hs = (x @ W1) * norm_src ; agg = scatter_add(hs[src] -> dst)
    gemm_kernel<false><<<512, 256, 0, stream>>>(x, W1, nullptr, nullptr, norm_src, hs);
    hipMemsetAsync(agg, 0, (size_t)NN * F * sizeof(float), stream);
    scatter_kernel<<<NE * 32 / 256, 256, 0, stream>>>(hs, src, dst, agg, NE);

    // layer 2: hs = (relu(agg*norm_dst + b1) @ W2) * norm_src ; agg = scatter
    gemm_kernel<true><<<512, 256, 0, stream>>>(agg, W2, b1, norm_dst, norm_src, hs);
    hipMemsetAsync(agg, 0, (size_t)NN * F * sizeof(float), stream);  // stream-ordered after gemm read
    scatter_kernel<<<NE * 32 / 256, 256, 0, stream>>>(hs, src, dst, agg, NE);

    // link head
    node_kernel<<<NN * 64 / 256, 256, 0, stream>>>(agg, norm_dst, b2, Wp, bufA, bufC, NN);
    score_kernel<<<(NE + 255) / 256, 256, 0, stream>>>(bufA, bufC, src, dst, bp, out, NE);
}

// Round 2
// 774.677 us; speedup vs baseline: 7.4269x; 7.4269x over previous
//
#include <hip/hip_runtime.h>
#include <cstdint>
#include <cstddef>

#define NN 100000
#define NE 1600000
#define F  128
#define NPAD 100352          // 98 * 1024
#define SCAN_BLOCKS 98       // NPAD / 1024

// ---------------- degree ----------------
__global__ void deg_kernel(const int* __restrict__ src, const int* __restrict__ dst,
                           int* __restrict__ deg_out, int* __restrict__ deg_in, int nE) {
    int e = blockIdx.x * blockDim.x + threadIdx.x;
    if (e < nE) {
        atomicAdd(&deg_out[src[e]], 1);
        atomicAdd(&deg_in[dst[e]], 1);
    }
}

__global__ void norm_kernel(const int* __restrict__ deg_out, const int* __restrict__ deg_in,
                            float* __restrict__ norm_src, float* __restrict__ norm_dst, int nN) {
    int n = blockIdx.x * blockDim.x + threadIdx.x;
    if (n < nN) {
        norm_src[n] = rsqrtf((float)max(deg_out[n], 1));
        norm_dst[n] = rsqrtf((float)max(deg_in[n], 1));
    }
}

// ---------------- counting-sort scan (deg_in -> exclusive offsets) ----------------
__global__ void scan_sums(const int* __restrict__ deg, int* __restrict__ bsums) {
    const int b = blockIdx.x, tid = threadIdx.x;
    int s = 0;
    #pragma unroll
    for (int k = 0; k < 4; ++k) {
        int g = b * 1024 + tid * 4 + k;
        s += (g < NN) ? deg[g] : 0;
    }
    __shared__ int sc[256];
    sc[tid] = s; __syncthreads();
    for (int off = 128; off > 0; off >>= 1) {
        if (tid < off) sc[tid] += sc[tid + off];
        __syncthreads();
    }
    if (tid == 0) bsums[b] = sc[0];
}

__global__ void scan_top(int* __restrict__ bsums) {
    if (threadIdx.x == 0 && blockIdx.x == 0) {
        int run = 0;
        for (int i = 0; i < SCAN_BLOCKS; ++i) { int v = bsums[i]; bsums[i] = run; run += v; }
    }
}

__global__ void scan_final(const int* __restrict__ deg, const int* __restrict__ bsums,
                           int* __restrict__ offsets, int* __restrict__ cursor) {
    const int b = blockIdx.x, tid = threadIdx.x;
    int d[4], s = 0;
    #pragma unroll
    for (int k = 0; k < 4; ++k) {
        int g = b * 1024 + tid * 4 + k;
        d[k] = (g < NN) ? deg[g] : 0;
        s += d[k];
    }
    __shared__ int sc[256];
    sc[tid] = s; __syncthreads();
    // Hillis-Steele inclusive scan over 256 thread-sums
    for (int off = 1; off < 256; off <<= 1) {
        int v = (tid >= off) ? sc[tid - off] : 0;
        __syncthreads();
        sc[tid] += v;
        __syncthreads();
    }
    int excl = bsums[b] + sc[tid] - s;
    #pragma unroll
    for (int k = 0; k < 4; ++k) {
        int g = b * 1024 + tid * 4 + k;
        if (g <= NN) { offsets[g] = excl; if (g < NN) cursor[g] = excl; }
        excl += d[k];
    }
}

// ---------------- fill: sorted_src grouped by dst ----------------
__global__ void fill_kernel(const int* __restrict__ src, const int* __restrict__ dst,
                            int* __restrict__ cursor, int* __restrict__ sorted_src, int nE) {
    int e = blockIdx.x * blockDim.x + threadIdx.x;
    if (e < nE) {
        int p = atomicAdd(&cursor[dst[e]], 1);
        sorted_src[p] = src[e];
    }
}

// ---------------- fused GEMM: out[n][:] = (pre(in[n][:]) @ W) * norm_src[n] ----------------
template<bool PRE>
__global__ __launch_bounds__(256, 2)
void gemm_kernel(const float* __restrict__ in, const float* __restrict__ W,
                 const float* __restrict__ b_pre, const float* __restrict__ norm_dst,
                 const float* __restrict__ norm_src, float* __restrict__ out) {
    __shared__ __align__(16) float Ws[F * F];      // 64 KB [k][c]
    __shared__ __align__(16) float xs[32][F];      // 16 KB

    const int tid = threadIdx.x;
    for (int i = tid * 4; i < F * F; i += 256 * 4) {
        *(float4*)&Ws[i] = *(const float4*)&W[i];
    }

    const int l  = tid & 63;
    const int w  = tid >> 6;
    const int cg = l & 31;
    const int rg = l >> 5;
    const int c0 = cg * 4;

    const int nTiles = NN / 32;     // 3125 exact
    for (int tile = blockIdx.x; tile < nTiles; tile += gridDim.x) {
        const int row0 = tile * 32;
        __syncthreads();
        for (int i = tid; i < 32 * 32; i += 256) {
            const int r  = i >> 5;
            const int k4 = (i & 31) * 4;
            float4 v = *(const float4*)&in[(size_t)(row0 + r) * F + k4];
            if constexpr (PRE) {
                const float nd = norm_dst[row0 + r];
                const float4 bb = *(const float4*)&b_pre[k4];
                v.x = fmaxf(v.x * nd + bb.x, 0.f);
                v.y = fmaxf(v.y * nd + bb.y, 0.f);
                v.z = fmaxf(v.z * nd + bb.z, 0.f);
                v.w = fmaxf(v.w * nd + bb.w, 0.f);
            }
            *(float4*)&xs[r][k4] = v;
        }
        __syncthreads();

        const int r0 = 8 * w + 4 * rg;
        float4 a0 = {0,0,0,0}, a1 = {0,0,0,0}, a2 = {0,0,0,0}, a3 = {0,0,0,0};
        #pragma unroll 8
        for (int k = 0; k < F; ++k) {
            const float4 wv = *(const float4*)&Ws[k * F + c0];
            const float x0 = xs[r0 + 0][k];
            const float x1 = xs[r0 + 1][k];
            const float x2 = xs[r0 + 2][k];
            const float x3 = xs[r0 + 3][k];
            a0.x += x0 * wv.x; a0.y += x0 * wv.y; a0.z += x0 * wv.z; a0.w += x0 * wv.w;
            a1.x += x1 * wv.x; a1.y += x1 * wv.y; a1.z += x1 * wv.z; a1.w += x1 * wv.w;
            a2.x += x2 * wv.x; a2.y += x2 * wv.y; a2.z += x2 * wv.z; a2.w += x2 * wv.w;
            a3.x += x3 * wv.x; a3.y += x3 * wv.y; a3.z += x3 * wv.z; a3.w += x3 * wv.w;
        }
        {
            const float ns0 = norm_src[row0 + r0 + 0];
            const float ns1 = norm_src[row0 + r0 + 1];
            const float ns2 = norm_src[row0 + r0 + 2];
            const float ns3 = norm_src[row0 + r0 + 3];
            float4 o;
            o.x = a0.x*ns0; o.y = a0.y*ns0; o.z = a0.z*ns0; o.w = a0.w*ns0;
            *(float4*)&out[(size_t)(row0 + r0 + 0) * F + c0] = o;
            o.x = a1.x*ns1; o.y = a1.y*ns1; o.z = a1.z*ns1; o.w = a1.w*ns1;
            *(float4*)&out[(size_t)(row0 + r0 + 1) * F + c0] = o;
            o.x = a2.x*ns2; o.y = a2.y*ns2; o.z = a2.z*ns2; o.w = a2.w*ns2;
            *(float4*)&out[(size_t)(row0 + r0 + 2) * F + c0] = o;
            o.x = a3.x*ns3; o.y = a3.y*ns3; o.z = a3.z*ns3; o.w = a3.w*ns3;
            *(float4*)&out[(size_t)(row0 + r0 + 3) * F + c0] = o;
        }
    }
}

// ---------------- gather aggregate: agg[n][:] = sum_{e: dst[e]=n} hs[sorted_src[e]][:] ----------------
// one wave per node; float2 per lane
__global__ __launch_bounds__(256)
void gather_kernel(const float* __restrict__ hs, const int* __restrict__ sorted_src,
                   const int* __restrict__ offsets, float* __restrict__ agg, int nN) {
    const int gid = blockIdx.x * blockDim.x + threadIdx.x;
    const int n = gid >> 6;
    const int l = gid & 63;
    if (n >= nN) return;
    const int beg = offsets[n];
    const int end = offsets[n + 1];
    float2 acc = {0.f, 0.f};
    const int c = 2 * l;
    int j = beg;
    for (; j + 4 <= end; j += 4) {
        const int s0 = sorted_src[j + 0];   // same addr across wave -> broadcast load
        const int s1 = sorted_src[j + 1];
        const int s2 = sorted_src[j + 2];
        const int s3 = sorted_src[j + 3];
        const float2 v0 = *(const float2*)&hs[(size_t)s0 * F + c];
        const float2 v1 = *(const float2*)&hs[(size_t)s1 * F + c];
        const float2 v2 = *(const float2*)&hs[(size_t)s2 * F + c];
        const float2 v3 = *(const float2*)&hs[(size_t)s3 * F + c];
        acc.x += v0.x + v1.x + v2.x + v3.x;
        acc.y += v0.y + v1.y + v2.y + v3.y;
    }
    for (; j < end; ++j) {
        const int s = sorted_src[j];
        const float2 v = *(const float2*)&hs[(size_t)s * F + c];
        acc.x += v.x;
        acc.y += v.y;
    }
    *(float2*)&agg[(size_t)n * F + c] = acc;
}

// ---------------- link-head per-node partials ----------------
__global__ void node_kernel(const float* __restrict__ agg, const float* __restrict__ norm_dst,
                            const float* __restrict__ b2, const float* __restrict__ Wp,
                            float* __restrict__ a, float* __restrict__ c, int nN) {
    const int gid = blockIdx.x * blockDim.x + threadIdx.x;
    const int n = gid >> 6;
    const int l = gid & 63;
    if (n < nN) {
        const float nd = norm_dst[n];
        const float2 v  = *(const float2*)&agg[(size_t)n * F + 2 * l];
        const float2 bb = *(const float2*)&b2[2 * l];
        const float h0 = v.x * nd + bb.x;
        const float h1 = v.y * nd + bb.y;
        const float2 wa = *(const float2*)&Wp[2 * l];
        const float2 wc = *(const float2*)&Wp[F + 2 * l];
        float pa = h0 * wa.x + h1 * wa.y;
        float pc = h0 * wc.x + h1 * wc.y;
        #pragma unroll
        for (int off = 32; off > 0; off >>= 1) {
            pa += __shfl_xor(pa, off);
            pc += __shfl_xor(pc, off);
        }
        if (l == 0) { a[n] = pa; c[n] = pc; }
    }
}

// ---------------- edge scores ----------------
__global__ void score_kernel(const float* __restrict__ a, const float* __restrict__ c,
                             const int* __restrict__ src, const int* __restrict__ dst,
                             const float* __restrict__ bp, float* __restrict__ out, int nE) {
    const int e = blockIdx.x * blockDim.x + threadIdx.x;
    if (e < nE) {
        const float z = a[src[e]] + c[dst[e]] + bp[0];
        out[e] = 1.f / (1.f + expf(-z));
    }
}

extern "C" void kernel_launch(void* const* d_in, const int* in_sizes, int n_in,
                              void* d_out, int out_size, void* d_ws, size_t ws_size,
                              hipStream_t stream) {
    const float* x  = (const float*)d_in[0];
    const float* W1 = (const float*)d_in[1];
    const float* b1 = (const float*)d_in[2];
    const float* W2 = (const float*)d_in[3];
    const float* b2 = (const float*)d_in[4];
    const float* Wp = (const float*)d_in[5];
    const float* bp = (const float*)d_in[6];
    const int*   src = (const int*)d_in[7];
    const int*   dst = (const int*)d_in[8];
    float* out = (float*)d_out;

    float* ws       = (float*)d_ws;
    float* norm_src = ws;                       // NPAD
    float* norm_dst = ws + NPAD;                // NPAD
    float* bufA     = ws + 2 * NPAD;            // NPAD: deg_out, later a[]
    float* bufC     = ws + 3 * NPAD;            // NPAD: deg_in, later c[]
    int*   offsets  = (int*)(ws + 4 * NPAD);    // NPAD + 4
    int*   cursor   = offsets + NPAD + 4;       // NPAD
    int*   sorted   = cursor + NPAD;            // NE
    int*   bsums    = sorted + NE;              // 128
    float* hs       = (float*)(bsums + 128);    // NN*F
    float* agg      = hs + (size_t)NN * F;      // NN*F

    // degrees -> norms
    hipMemsetAsync(bufA, 0, 2 * NPAD * sizeof(float), stream);
    deg_kernel<<<(NE + 255) / 256, 256, 0, stream>>>(src, dst, (int*)bufA, (int*)bufC, NE);
    norm_kernel<<<(NN + 255) / 256, 256, 0, stream>>>((int*)bufA, (int*)bufC, norm_src, norm_dst, NN);

    // counting sort by dst -> CSR (built once, used by both layers)
    scan_sums<<<SCAN_BLOCKS, 256, 0, stream>>>((const int*)bufC, bsums);
    scan_top<<<1, 64, 0, stream>>>(bsums);
    scan_final<<<SCAN_BLOCKS, 256, 0, stream>>>((const int*)bufC, bsums, offsets, cursor);
    fill_kernel<<<(NE + 255) / 256, 256, 0, stream>>>(src, dst, cursor, sorted, NE);

    // layer 1: hs = (x @ W1) * norm_src ; agg = gather
    gemm_kernel<false><<<512, 256, 0, stream>>>(x, W1, nullptr, nullptr, norm_src, hs);
    gather_kernel<<<NN * 64 / 256, 256, 0, stream>>>(hs, sorted, offsets, agg, NN);

    // layer 2: hs = (relu(agg*norm_dst + b1) @ W2) * norm_src ; agg = gather
    gemm_kernel<true><<<512, 256, 0, stream>>>(agg, W2, b1, norm_dst, norm_src, hs);
    gather_kernel<<<NN * 64 / 256, 256, 0, stream>>>(hs, sorted, offsets, agg, NN);

    // link head
    node_kernel<<<NN * 64 / 256, 256, 0, stream>>>(agg, norm_dst, b2, Wp, bufA, bufC, NN);
    score_kernel<<<(NE + 255) / 256, 256, 0, stream>>>(bufA, bufC, src, dst, bp, out, NE);
}

// Round 3
// 690.758 us; speedup vs baseline: 8.3292x; 1.1215x over previous
//
#include <hip/hip_runtime.h>
#include <cstdint>
#include <cstddef>

#define NN 100000
#define NE 1600000
#define F  128
#define NPAD 100352          // 98 * 1024
#define SCAN_BLOCKS 98       // NPAD / 1024

// ---------------- degree ----------------
__global__ void deg_kernel(const int* __restrict__ src, const int* __restrict__ dst,
                           int* __restrict__ deg_out, int* __restrict__ deg_in, int nE) {
    int e = blockIdx.x * blockDim.x + threadIdx.x;
    if (e < nE) {
        atomicAdd(&deg_out[src[e]], 1);
        atomicAdd(&deg_in[dst[e]], 1);
    }
}

__global__ void norm_kernel(const int* __restrict__ deg_out, const int* __restrict__ deg_in,
                            float* __restrict__ norm_src, float* __restrict__ norm_dst, int nN) {
    int n = blockIdx.x * blockDim.x + threadIdx.x;
    if (n < nN) {
        norm_src[n] = rsqrtf((float)max(deg_out[n], 1));
        norm_dst[n] = rsqrtf((float)max(deg_in[n], 1));
    }
}

// ---------------- counting-sort scan (deg_in -> exclusive offsets) ----------------
__global__ void scan_sums(const int* __restrict__ deg, int* __restrict__ bsums) {
    const int b = blockIdx.x, tid = threadIdx.x;
    int s = 0;
    #pragma unroll
    for (int k = 0; k < 4; ++k) {
        int g = b * 1024 + tid * 4 + k;
        s += (g < NN) ? deg[g] : 0;
    }
    __shared__ int sc[256];
    sc[tid] = s; __syncthreads();
    for (int off = 128; off > 0; off >>= 1) {
        if (tid < off) sc[tid] += sc[tid + off];
        __syncthreads();
    }
    if (tid == 0) bsums[b] = sc[0];
}

__global__ void scan_top(int* __restrict__ bsums) {
    if (threadIdx.x == 0 && blockIdx.x == 0) {
        int run = 0;
        for (int i = 0; i < SCAN_BLOCKS; ++i) { int v = bsums[i]; bsums[i] = run; run += v; }
    }
}

__global__ void scan_final(const int* __restrict__ deg, const int* __restrict__ bsums,
                           int* __restrict__ offsets, int* __restrict__ cursor) {
    const int b = blockIdx.x, tid = threadIdx.x;
    int d[4], s = 0;
    #pragma unroll
    for (int k = 0; k < 4; ++k) {
        int g = b * 1024 + tid * 4 + k;
        d[k] = (g < NN) ? deg[g] : 0;
        s += d[k];
    }
    __shared__ int sc[256];
    sc[tid] = s; __syncthreads();
    for (int off = 1; off < 256; off <<= 1) {
        int v = (tid >= off) ? sc[tid - off] : 0;
        __syncthreads();
        sc[tid] += v;
        __syncthreads();
    }
    int excl = bsums[b] + sc[tid] - s;
    #pragma unroll
    for (int k = 0; k < 4; ++k) {
        int g = b * 1024 + tid * 4 + k;
        if (g <= NN) { offsets[g] = excl; if (g < NN) cursor[g] = excl; }
        excl += d[k];
    }
}

// ---------------- fused gemm1 + fill ----------------
// blockIdx%3==2  -> fill role:  CSR bucket fill via atomic cursors (latency-bound)
// blockIdx%3 !=2 -> gemm role:  out[n][:] = (in[n][:] @ W) * norm_src[n]  (VALU-bound)
// Independent work co-resident per CU so fill's latency hides under gemm compute.
__global__ __launch_bounds__(256, 2)
void gemm1_fill_kernel(const float* __restrict__ in, const float* __restrict__ W,
                       const float* __restrict__ norm_src, float* __restrict__ out,
                       const int* __restrict__ src, const int* __restrict__ dst,
                       int* __restrict__ cursor, int* __restrict__ sorted_src) {
    __shared__ __align__(16) float Ws[F * F];      // 64 KB [k][c]
    __shared__ __align__(16) float xs[32][F];      // 16 KB

    const int g = blockIdx.x;
    const int r3 = g % 3;
    const int tid = threadIdx.x;

    if (r3 == 2) {                                  // ---- fill role (256 blocks)
        const int fid = g / 3;
        for (int e = fid * 256 + tid; e < NE; e += 256 * 256) {
            int p = atomicAdd(&cursor[dst[e]], 1);
            sorted_src[p] = src[e];
        }
        return;
    }

    const int gid = (g / 3) * 2 + r3;               // ---- gemm role (512 blocks)
    for (int i = tid * 4; i < F * F; i += 256 * 4) {
        *(float4*)&Ws[i] = *(const float4*)&W[i];
    }

    const int l  = tid & 63;
    const int w  = tid >> 6;
    const int cg = l & 31;
    const int rg = l >> 5;
    const int c0 = cg * 4;

    const int nTiles = NN / 32;                     // 3125
    for (int tile = gid; tile < nTiles; tile += 512) {
        const int row0 = tile * 32;
        __syncthreads();
        for (int i = tid; i < 32 * 32; i += 256) {
            const int r  = i >> 5;
            const int k4 = (i & 31) * 4;
            *(float4*)&xs[r][k4] = *(const float4*)&in[(size_t)(row0 + r) * F + k4];
        }
        __syncthreads();

        const int r0 = 8 * w + 4 * rg;
        float4 a0 = {0,0,0,0}, a1 = {0,0,0,0}, a2 = {0,0,0,0}, a3 = {0,0,0,0};
        #pragma unroll 8
        for (int k = 0; k < F; ++k) {
            const float4 wv = *(const float4*)&Ws[k * F + c0];
            const float x0 = xs[r0 + 0][k];
            const float x1 = xs[r0 + 1][k];
            const float x2 = xs[r0 + 2][k];
            const float x3 = xs[r0 + 3][k];
            a0.x += x0 * wv.x; a0.y += x0 * wv.y; a0.z += x0 * wv.z; a0.w += x0 * wv.w;
            a1.x += x1 * wv.x; a1.y += x1 * wv.y; a1.z += x1 * wv.z; a1.w += x1 * wv.w;
            a2.x += x2 * wv.x; a2.y += x2 * wv.y; a2.z += x2 * wv.z; a2.w += x2 * wv.w;
            a3.x += x3 * wv.x; a3.y += x3 * wv.y; a3.z += x3 * wv.z; a3.w += x3 * wv.w;
        }
        const float ns0 = norm_src[row0 + r0 + 0];
        const float ns1 = norm_src[row0 + r0 + 1];
        const float ns2 = norm_src[row0 + r0 + 2];
        const float ns3 = norm_src[row0 + r0 + 3];
        float4 o;
        o.x = a0.x*ns0; o.y = a0.y*ns0; o.z = a0.z*ns0; o.w = a0.w*ns0;
        *(float4*)&out[(size_t)(row0 + r0 + 0) * F + c0] = o;
        o.x = a1.x*ns1; o.y = a1.y*ns1; o.z = a1.z*ns1; o.w = a1.w*ns1;
        *(float4*)&out[(size_t)(row0 + r0 + 1) * F + c0] = o;
        o.x = a2.x*ns2; o.y = a2.y*ns2; o.z = a2.z*ns2; o.w = a2.w*ns2;
        *(float4*)&out[(size_t)(row0 + r0 + 2) * F + c0] = o;
        o.x = a3.x*ns3; o.y = a3.y*ns3; o.z = a3.z*ns3; o.w = a3.w*ns3;
        *(float4*)&out[(size_t)(row0 + r0 + 3) * F + c0] = o;
    }
}

// ---------------- plain GEMM (layer 2): out = (in @ W) * norm_src ----------------
__global__ __launch_bounds__(256, 2)
void gemm_kernel(const float* __restrict__ in, const float* __restrict__ W,
                 const float* __restrict__ norm_src, float* __restrict__ out) {
    __shared__ __align__(16) float Ws[F * F];
    __shared__ __align__(16) float xs[32][F];

    const int tid = threadIdx.x;
    for (int i = tid * 4; i < F * F; i += 256 * 4) {
        *(float4*)&Ws[i] = *(const float4*)&W[i];
    }

    const int l  = tid & 63;
    const int w  = tid >> 6;
    const int cg = l & 31;
    const int rg = l >> 5;
    const int c0 = cg * 4;

    const int nTiles = NN / 32;
    for (int tile = blockIdx.x; tile < nTiles; tile += gridDim.x) {
        const int row0 = tile * 32;
        __syncthreads();
        for (int i = tid; i < 32 * 32; i += 256) {
            const int r  = i >> 5;
            const int k4 = (i & 31) * 4;
            *(float4*)&xs[r][k4] = *(const float4*)&in[(size_t)(row0 + r) * F + k4];
        }
        __syncthreads();

        const int r0 = 8 * w + 4 * rg;
        float4 a0 = {0,0,0,0}, a1 = {0,0,0,0}, a2 = {0,0,0,0}, a3 = {0,0,0,0};
        #pragma unroll 8
        for (int k = 0; k < F; ++k) {
            const float4 wv = *(const float4*)&Ws[k * F + c0];
            const float x0 = xs[r0 + 0][k];
            const float x1 = xs[r0 + 1][k];
            const float x2 = xs[r0 + 2][k];
            const float x3 = xs[r0 + 3][k];
            a0.x += x0 * wv.x; a0.y += x0 * wv.y; a0.z += x0 * wv.z; a0.w += x0 * wv.w;
            a1.x += x1 * wv.x; a1.y += x1 * wv.y; a1.z += x1 * wv.z; a1.w += x1 * wv.w;
            a2.x += x2 * wv.x; a2.y += x2 * wv.y; a2.z += x2 * wv.z; a2.w += x2 * wv.w;
            a3.x += x3 * wv.x; a3.y += x3 * wv.y; a3.z += x3 * wv.z; a3.w += x3 * wv.w;
        }
        const float ns0 = norm_src[row0 + r0 + 0];
        const float ns1 = norm_src[row0 + r0 + 1];
        const float ns2 = norm_src[row0 + r0 + 2];
        const float ns3 = norm_src[row0 + r0 + 3];
        float4 o;
        o.x = a0.x*ns0; o.y = a0.y*ns0; o.z = a0.z*ns0; o.w = a0.w*ns0;
        *(float4*)&out[(size_t)(row0 + r0 + 0) * F + c0] = o;
        o.x = a1.x*ns1; o.y = a1.y*ns1; o.z = a1.z*ns1; o.w = a1.w*ns1;
        *(float4*)&out[(size_t)(row0 + r0 + 1) * F + c0] = o;
        o.x = a2.x*ns2; o.y = a2.y*ns2; o.z = a2.z*ns2; o.w = a2.w*ns2;
        *(float4*)&out[(size_t)(row0 + r0 + 2) * F + c0] = o;
        o.x = a3.x*ns3; o.y = a3.y*ns3; o.z = a3.z*ns3; o.w = a3.w*ns3;
        *(float4*)&out[(size_t)(row0 + r0 + 3) * F + c0] = o;
    }
}

// ---------------- gather aggregate (pair scheme: 2 edges per wave, float4/lane) ----------------
// EPI 0: outv[n][:] = relu(acc*norm_dst[n] + bias)      (layer-1 -> layer-2 input, pre-activated)
// EPI 1: a[n] = h2·Wp[:128], c[n] = h2·Wp[128:], h2 = acc*norm_dst[n] + bias   (head partials)
template<int EPI>
__global__ __launch_bounds__(256)
void gather_kernel(const float* __restrict__ hs, const int* __restrict__ sorted_src,
                   const int* __restrict__ offsets, const float* __restrict__ norm_dst,
                   const float* __restrict__ bias, const float* __restrict__ Wp,
                   float* __restrict__ outv, float* __restrict__ outa, float* __restrict__ outc,
                   int nN) {
    const int gid = blockIdx.x * blockDim.x + threadIdx.x;
    const int n = gid >> 6;
    if (n >= nN) return;
    const int l    = threadIdx.x & 63;
    const int half = l >> 5;                // which edge of the pair
    const int c0   = (l & 31) * 4;          // float4 column slot
    const int beg = offsets[n];
    const int end = offsets[n + 1];

    float4 acc = {0.f, 0.f, 0.f, 0.f};
    int j = beg;
    for (; j + 8 <= end; j += 8) {          // 8 edges in flight per wave
        const int s0 = sorted_src[j + 0 + half];
        const int s1 = sorted_src[j + 2 + half];
        const int s2 = sorted_src[j + 4 + half];
        const int s3 = sorted_src[j + 6 + half];
        const float4 v0 = *(const float4*)&hs[(size_t)s0 * F + c0];
        const float4 v1 = *(const float4*)&hs[(size_t)s1 * F + c0];
        const float4 v2 = *(const float4*)&hs[(size_t)s2 * F + c0];
        const float4 v3 = *(const float4*)&hs[(size_t)s3 * F + c0];
        acc.x += v0.x + v1.x + v2.x + v3.x;
        acc.y += v0.y + v1.y + v2.y + v3.y;
        acc.z += v0.z + v1.z + v2.z + v3.z;
        acc.w += v0.w + v1.w + v2.w + v3.w;
    }
    for (; j < end; j += 2) {
        if (j + half < end) {
            const int s = sorted_src[j + half];
            const float4 v = *(const float4*)&hs[(size_t)s * F + c0];
            acc.x += v.x; acc.y += v.y; acc.z += v.z; acc.w += v.w;
        }
    }
    // merge the two halves
    acc.x += __shfl_xor(acc.x, 32);
    acc.y += __shfl_xor(acc.y, 32);
    acc.z += __shfl_xor(acc.z, 32);
    acc.w += __shfl_xor(acc.w, 32);

    if constexpr (EPI == 0) {
        if (half == 0) {
            const float nd = norm_dst[n];
            const float4 bb = *(const float4*)&bias[c0];
            float4 o;
            o.x = fmaxf(acc.x * nd + bb.x, 0.f);
            o.y = fmaxf(acc.y * nd + bb.y, 0.f);
            o.z = fmaxf(acc.z * nd + bb.z, 0.f);
            o.w = fmaxf(acc.w * nd + bb.w, 0.f);
            *(float4*)&outv[(size_t)n * F + c0] = o;
        }
    } else {
        const float nd = norm_dst[n];
        const float4 bb = *(const float4*)&bias[c0];
        const float hx = acc.x * nd + bb.x;
        const float hy = acc.y * nd + bb.y;
        const float hz = acc.z * nd + bb.z;
        const float hw = acc.w * nd + bb.w;
        const float4 wa = *(const float4*)&Wp[c0];
        const float4 wc = *(const float4*)&Wp[F + c0];
        float pa = hx * wa.x + hy * wa.y + hz * wa.z + hw * wa.w;
        float pc = hx * wc.x + hy * wc.y + hz * wc.z + hw * wc.w;
        #pragma unroll
        for (int m = 16; m > 0; m >>= 1) {
            pa += __shfl_xor(pa, m);
            pc += __shfl_xor(pc, m);
        }
        if (l == 0) { outa[n] = pa; outc[n] = pc; }
    }
}

// ---------------- edge scores ----------------
__global__ void score_kernel(const float* __restrict__ a, const float* __restrict__ c,
                             const int* __restrict__ src, const int* __restrict__ dst,
                             const float* __restrict__ bp, float* __restrict__ out, int nE) {
    const int e = blockIdx.x * blockDim.x + threadIdx.x;
    if (e < nE) {
        const float z = a[src[e]] + c[dst[e]] + bp[0];
        out[e] = 1.f / (1.f + __expf(-z));
    }
}

extern "C" void kernel_launch(void* const* d_in, const int* in_sizes, int n_in,
                              void* d_out, int out_size, void* d_ws, size_t ws_size,
                              hipStream_t stream) {
    const float* x  = (const float*)d_in[0];
    const float* W1 = (const float*)d_in[1];
    const float* b1 = (const float*)d_in[2];
    const float* W2 = (const float*)d_in[3];
    const float* b2 = (const float*)d_in[4];
    const float* Wp = (const float*)d_in[5];
    const float* bp = (const float*)d_in[6];
    const int*   src = (const int*)d_in[7];
    const int*   dst = (const int*)d_in[8];
    float* out = (float*)d_out;

    float* ws       = (float*)d_ws;
    float* norm_src = ws;                       // NPAD
    float* norm_dst = ws + NPAD;                // NPAD
    float* bufA     = ws + 2 * NPAD;            // NPAD: deg_out, later a[]
    float* bufC     = ws + 3 * NPAD;            // NPAD: deg_in, later c[]
    int*   offsets  = (int*)(ws + 4 * NPAD);    // NPAD + 4
    int*   cursor   = offsets + NPAD + 4;       // NPAD
    int*   sorted   = cursor + NPAD;            // NE
    int*   bsums    = sorted + NE;              // 128
    float* hs       = (float*)(bsums + 128);    // NN*F
    float* agg      = hs + (size_t)NN * F;      // NN*F (pre-activated layer-2 input)

    // degrees -> norms
    hipMemsetAsync(bufA, 0, 2 * NPAD * sizeof(float), stream);
    deg_kernel<<<(NE + 255) / 256, 256, 0, stream>>>(src, dst, (int*)bufA, (int*)bufC, NE);
    norm_kernel<<<(NN + 255) / 256, 256, 0, stream>>>((int*)bufA, (int*)bufC, norm_src, norm_dst, NN);

    // CSR scan (counting sort by dst)
    scan_sums<<<SCAN_BLOCKS, 256, 0, stream>>>((const int*)bufC, bsums);
    scan_top<<<1, 64, 0, stream>>>(bsums);
    scan_final<<<SCAN_BLOCKS, 256, 0, stream>>>((const int*)bufC, bsums, offsets, cursor);

    // layer 1 GEMM overlapped with CSR fill (independent work, interleaved block roles)
    gemm1_fill_kernel<<<768, 256, 0, stream>>>(x, W1, norm_src, hs, src, dst, cursor, sorted);

    // gather1: agg = relu(sum(hs[src]) * norm_dst + b1)
    gather_kernel<0><<<NN * 64 / 256, 256, 0, stream>>>(hs, sorted, offsets, norm_dst, b1, nullptr,
                                                        agg, nullptr, nullptr, NN);

    // layer 2 GEMM: hs = (agg @ W2) * norm_src
    gemm_kernel<<<512, 256, 0, stream>>>(agg, W2, norm_src, hs);

    // gather2 fused with link-head partials: a[n], c[n]
    gather_kernel<1><<<NN * 64 / 256, 256, 0, stream>>>(hs, sorted, offsets, norm_dst, b2, Wp,
                                                        nullptr, bufA, bufC, NN);

    // edge scores
    score_kernel<<<(NE + 255) / 256, 256, 0, stream>>>(bufA, bufC, src, dst, bp, out, NE);
}

// Round 4
// 576.389 us; speedup vs baseline: 9.9819x; 1.1984x over previous
//
#include <hip/hip_runtime.h>
#include <cstdint>
#include <cstddef>

#define NN 100000
#define NE 1600000
#define F  128
#define NPAD 100352          // 98 * 1024
#define SCAN_BLOCKS 98       // NPAD / 1024

// bf16 storage helpers (RNE, finite values only)
__device__ __forceinline__ unsigned short f2bf(float f) {
    unsigned u = __float_as_uint(f);
    unsigned r = (u + 0x7fffu + ((u >> 16) & 1u)) >> 16;
    return (unsigned short)r;
}
__device__ __forceinline__ void acc_bf8(const uint4 v, float* acc) {
    acc[0] += __uint_as_float(v.x << 16);
    acc[1] += __uint_as_float(v.x & 0xffff0000u);
    acc[2] += __uint_as_float(v.y << 16);
    acc[3] += __uint_as_float(v.y & 0xffff0000u);
    acc[4] += __uint_as_float(v.z << 16);
    acc[5] += __uint_as_float(v.z & 0xffff0000u);
    acc[6] += __uint_as_float(v.w << 16);
    acc[7] += __uint_as_float(v.w & 0xffff0000u);
}

// ---------------- degree ----------------
__global__ void deg_kernel(const int* __restrict__ src, const int* __restrict__ dst,
                           int* __restrict__ deg_out, int* __restrict__ deg_in, int nE) {
    int e = blockIdx.x * blockDim.x + threadIdx.x;
    if (e < nE) {
        atomicAdd(&deg_out[src[e]], 1);
        atomicAdd(&deg_in[dst[e]], 1);
    }
}

__global__ void norm_kernel(const int* __restrict__ deg_out, const int* __restrict__ deg_in,
                            float* __restrict__ norm_src, float* __restrict__ norm_dst, int nN) {
    int n = blockIdx.x * blockDim.x + threadIdx.x;
    if (n < nN) {
        norm_src[n] = rsqrtf((float)max(deg_out[n], 1));
        norm_dst[n] = rsqrtf((float)max(deg_in[n], 1));
    }
}

// ---------------- counting-sort scan (deg_in -> exclusive offsets) ----------------
__global__ void scan_sums(const int* __restrict__ deg, int* __restrict__ bsums) {
    const int b = blockIdx.x, tid = threadIdx.x;
    int s = 0;
    #pragma unroll
    for (int k = 0; k < 4; ++k) {
        int g = b * 1024 + tid * 4 + k;
        s += (g < NN) ? deg[g] : 0;
    }
    __shared__ int sc[256];
    sc[tid] = s; __syncthreads();
    for (int off = 128; off > 0; off >>= 1) {
        if (tid < off) sc[tid] += sc[tid + off];
        __syncthreads();
    }
    if (tid == 0) bsums[b] = sc[0];
}

__global__ void scan_top(int* __restrict__ bsums) {
    if (threadIdx.x == 0 && blockIdx.x == 0) {
        int run = 0;
        for (int i = 0; i < SCAN_BLOCKS; ++i) { int v = bsums[i]; bsums[i] = run; run += v; }
    }
}

__global__ void scan_final(const int* __restrict__ deg, const int* __restrict__ bsums,
                           int* __restrict__ offsets, int* __restrict__ cursor) {
    const int b = blockIdx.x, tid = threadIdx.x;
    int d[4], s = 0;
    #pragma unroll
    for (int k = 0; k < 4; ++k) {
        int g = b * 1024 + tid * 4 + k;
        d[k] = (g < NN) ? deg[g] : 0;
        s += d[k];
    }
    __shared__ int sc[256];
    sc[tid] = s; __syncthreads();
    for (int off = 1; off < 256; off <<= 1) {
        int v = (tid >= off) ? sc[tid - off] : 0;
        __syncthreads();
        sc[tid] += v;
        __syncthreads();
    }
    int excl = bsums[b] + sc[tid] - s;
    #pragma unroll
    for (int k = 0; k < 4; ++k) {
        int g = b * 1024 + tid * 4 + k;
        if (g <= NN) { offsets[g] = excl; if (g < NN) cursor[g] = excl; }
        excl += d[k];
    }
}

// ---------------- fused gemm1 + fill ----------------
// blockIdx%3==2 -> fill role (256 blocks, 4 independent atomics in flight)
// else          -> gemm role (512 blocks): hs_bf[n][:] = bf16((x[n][:] @ W1) * norm_src[n])
__global__ __launch_bounds__(256, 2)
void gemm1_fill_kernel(const float* __restrict__ in, const float* __restrict__ W,
                       const float* __restrict__ norm_src, unsigned short* __restrict__ out_bf,
                       const int* __restrict__ src, const int* __restrict__ dst,
                       int* __restrict__ cursor, int* __restrict__ sorted_src) {
    __shared__ __align__(16) float Ws[F * F];      // 64 KB [k][c]
    __shared__ __align__(16) float xs[32][F];      // 16 KB

    const int g = blockIdx.x;
    const int r3 = g % 3;
    const int tid = threadIdx.x;

    if (r3 == 2) {                                  // ---- fill role
        const int S = 256 * 256;                    // 65536 threads
        const int base = (g / 3) * 256 + tid;
        int e = base;
        for (; e + 3 * S < NE; e += 4 * S) {
            const int d0 = dst[e], d1 = dst[e + S], d2 = dst[e + 2 * S], d3 = dst[e + 3 * S];
            const int s0 = src[e], s1 = src[e + S], s2 = src[e + 2 * S], s3 = src[e + 3 * S];
            const int p0 = atomicAdd(&cursor[d0], 1);
            const int p1 = atomicAdd(&cursor[d1], 1);
            const int p2 = atomicAdd(&cursor[d2], 1);
            const int p3 = atomicAdd(&cursor[d3], 1);
            __builtin_nontemporal_store(s0, &sorted_src[p0]);
            __builtin_nontemporal_store(s1, &sorted_src[p1]);
            __builtin_nontemporal_store(s2, &sorted_src[p2]);
            __builtin_nontemporal_store(s3, &sorted_src[p3]);
        }
        for (; e < NE; e += S) {
            const int p = atomicAdd(&cursor[dst[e]], 1);
            __builtin_nontemporal_store(src[e], &sorted_src[p]);
        }
        return;
    }

    const int gid = (g / 3) * 2 + r3;               // ---- gemm role (512 blocks)
    for (int i = tid * 4; i < F * F; i += 256 * 4) {
        *(float4*)&Ws[i] = *(const float4*)&W[i];
    }

    const int l  = tid & 63;
    const int w  = tid >> 6;
    const int cg = l & 31;
    const int rg = l >> 5;
    const int c0 = cg * 4;

    const int nTiles = NN / 32;                     // 3125
    for (int tile = gid; tile < nTiles; tile += 512) {
        const int row0 = tile * 32;
        __syncthreads();
        for (int i = tid; i < 32 * 32; i += 256) {
            const int r  = i >> 5;
            const int k4 = (i & 31) * 4;
            *(float4*)&xs[r][k4] = *(const float4*)&in[(size_t)(row0 + r) * F + k4];
        }
        __syncthreads();

        const int r0 = 8 * w + 4 * rg;
        float4 a0 = {0,0,0,0}, a1 = {0,0,0,0}, a2 = {0,0,0,0}, a3 = {0,0,0,0};
        #pragma unroll 8
        for (int k = 0; k < F; ++k) {
            const float4 wv = *(const float4*)&Ws[k * F + c0];
            const float x0 = xs[r0 + 0][k];
            const float x1 = xs[r0 + 1][k];
            const float x2 = xs[r0 + 2][k];
            const float x3 = xs[r0 + 3][k];
            a0.x += x0 * wv.x; a0.y += x0 * wv.y; a0.z += x0 * wv.z; a0.w += x0 * wv.w;
            a1.x += x1 * wv.x; a1.y += x1 * wv.y; a1.z += x1 * wv.z; a1.w += x1 * wv.w;
            a2.x += x2 * wv.x; a2.y += x2 * wv.y; a2.z += x2 * wv.z; a2.w += x2 * wv.w;
            a3.x += x3 * wv.x; a3.y += x3 * wv.y; a3.z += x3 * wv.z; a3.w += x3 * wv.w;
        }
        const float ns0 = norm_src[row0 + r0 + 0];
        const float ns1 = norm_src[row0 + r0 + 1];
        const float ns2 = norm_src[row0 + r0 + 2];
        const float ns3 = norm_src[row0 + r0 + 3];
        ushort4 o;
        o.x = f2bf(a0.x*ns0); o.y = f2bf(a0.y*ns0); o.z = f2bf(a0.z*ns0); o.w = f2bf(a0.w*ns0);
        *(ushort4*)&out_bf[(size_t)(row0 + r0 + 0) * F + c0] = o;
        o.x = f2bf(a1.x*ns1); o.y = f2bf(a1.y*ns1); o.z = f2bf(a1.z*ns1); o.w = f2bf(a1.w*ns1);
        *(ushort4*)&out_bf[(size_t)(row0 + r0 + 1) * F + c0] = o;
        o.x = f2bf(a2.x*ns2); o.y = f2bf(a2.y*ns2); o.z = f2bf(a2.z*ns2); o.w = f2bf(a2.w*ns2);
        *(ushort4*)&out_bf[(size_t)(row0 + r0 + 2) * F + c0] = o;
        o.x = f2bf(a3.x*ns3); o.y = f2bf(a3.y*ns3); o.z = f2bf(a3.z*ns3); o.w = f2bf(a3.w*ns3);
        *(ushort4*)&out_bf[(size_t)(row0 + r0 + 3) * F + c0] = o;
    }
}

// ---------------- plain GEMM (layer 2): hs_bf = bf16((agg @ W2) * norm_src) ----------------
__global__ __launch_bounds__(256, 2)
void gemm_kernel(const float* __restrict__ in, const float* __restrict__ W,
                 const float* __restrict__ norm_src, unsigned short* __restrict__ out_bf) {
    __shared__ __align__(16) float Ws[F * F];
    __shared__ __align__(16) float xs[32][F];

    const int tid = threadIdx.x;
    for (int i = tid * 4; i < F * F; i += 256 * 4) {
        *(float4*)&Ws[i] = *(const float4*)&W[i];
    }

    const int l  = tid & 63;
    const int w  = tid >> 6;
    const int cg = l & 31;
    const int rg = l >> 5;
    const int c0 = cg * 4;

    const int nTiles = NN / 32;
    for (int tile = blockIdx.x; tile < nTiles; tile += gridDim.x) {
        const int row0 = tile * 32;
        __syncthreads();
        for (int i = tid; i < 32 * 32; i += 256) {
            const int r  = i >> 5;
            const int k4 = (i & 31) * 4;
            *(float4*)&xs[r][k4] = *(const float4*)&in[(size_t)(row0 + r) * F + k4];
        }
        __syncthreads();

        const int r0 = 8 * w + 4 * rg;
        float4 a0 = {0,0,0,0}, a1 = {0,0,0,0}, a2 = {0,0,0,0}, a3 = {0,0,0,0};
        #pragma unroll 8
        for (int k = 0; k < F; ++k) {
            const float4 wv = *(const float4*)&Ws[k * F + c0];
            const float x0 = xs[r0 + 0][k];
            const float x1 = xs[r0 + 1][k];
            const float x2 = xs[r0 + 2][k];
            const float x3 = xs[r0 + 3][k];
            a0.x += x0 * wv.x; a0.y += x0 * wv.y; a0.z += x0 * wv.z; a0.w += x0 * wv.w;
            a1.x += x1 * wv.x; a1.y += x1 * wv.y; a1.z += x1 * wv.z; a1.w += x1 * wv.w;
            a2.x += x2 * wv.x; a2.y += x2 * wv.y; a2.z += x2 * wv.z; a2.w += x2 * wv.w;
            a3.x += x3 * wv.x; a3.y += x3 * wv.y; a3.z += x3 * wv.z; a3.w += x3 * wv.w;
        }
        const float ns0 = norm_src[row0 + r0 + 0];
        const float ns1 = norm_src[row0 + r0 + 1];
        const float ns2 = norm_src[row0 + r0 + 2];
        const float ns3 = norm_src[row0 + r0 + 3];
        ushort4 o;
        o.x = f2bf(a0.x*ns0); o.y = f2bf(a0.y*ns0); o.z = f2bf(a0.z*ns0); o.w = f2bf(a0.w*ns0);
        *(ushort4*)&out_bf[(size_t)(row0 + r0 + 0) * F + c0] = o;
        o.x = f2bf(a1.x*ns1); o.y = f2bf(a1.y*ns1); o.z = f2bf(a1.z*ns1); o.w = f2bf(a1.w*ns1);
        *(ushort4*)&out_bf[(size_t)(row0 + r0 + 1) * F + c0] = o;
        o.x = f2bf(a2.x*ns2); o.y = f2bf(a2.y*ns2); o.z = f2bf(a2.z*ns2); o.w = f2bf(a2.w*ns2);
        *(ushort4*)&out_bf[(size_t)(row0 + r0 + 2) * F + c0] = o;
        o.x = f2bf(a3.x*ns3); o.y = f2bf(a3.y*ns3); o.z = f2bf(a3.z*ns3); o.w = f2bf(a3.w*ns3);
        *(ushort4*)&out_bf[(size_t)(row0 + r0 + 3) * F + c0] = o;
    }
}

// ---------------- gather aggregate over bf16 rows ----------------
// one wave per node; 16 lanes per edge (8 bf16 cols each) -> 4 edges in flight, 8 with unroll
// EPI 0: agg[n][:] = relu(acc*norm_dst[n] + bias)            (fp32, layer-2 input)
// EPI 1: a[n] = h2·Wp[:128], c[n] = h2·Wp[128:]              (head partials)
template<int EPI>
__global__ __launch_bounds__(256)
void gather_kernel(const unsigned short* __restrict__ hs, const int* __restrict__ sorted_src,
                   const int* __restrict__ offsets, const float* __restrict__ norm_dst,
                   const float* __restrict__ bias, const float* __restrict__ Wp,
                   float* __restrict__ outv, float* __restrict__ outa, float* __restrict__ outc,
                   int nN) {
    const int gid = blockIdx.x * blockDim.x + threadIdx.x;
    const int n = gid >> 6;
    if (n >= nN) return;
    const int l  = threadIdx.x & 63;
    const int q  = l >> 4;                  // quarter: which edge of the 4-group
    const int c8 = (l & 15) * 8;            // 8 bf16 cols per lane
    const int beg = offsets[n];
    const int end = offsets[n + 1];

    float acc[8] = {0.f, 0.f, 0.f, 0.f, 0.f, 0.f, 0.f, 0.f};
    int j = beg;
    for (; j + 8 <= end; j += 8) {          // 8 edges in flight per wave
        const int s0 = sorted_src[j + q];
        const int s1 = sorted_src[j + 4 + q];
        const uint4 v0 = *(const uint4*)&hs[(size_t)s0 * F + c8];
        const uint4 v1 = *(const uint4*)&hs[(size_t)s1 * F + c8];
        acc_bf8(v0, acc);
        acc_bf8(v1, acc);
    }
    for (; j + 4 <= end; j += 4) {
        const int s = sorted_src[j + q];
        const uint4 v = *(const uint4*)&hs[(size_t)s * F + c8];
        acc_bf8(v, acc);
    }
    if (j + q < end) {
        const int s = sorted_src[j + q];
        const uint4 v = *(const uint4*)&hs[(size_t)s * F + c8];
        acc_bf8(v, acc);
    }
    // merge the four quarters (lanes l, l^16, l^32, l^48 hold partials for the same cols)
    #pragma unroll
    for (int k = 0; k < 8; ++k) {
        acc[k] += __shfl_xor(acc[k], 16);
        acc[k] += __shfl_xor(acc[k], 32);
    }

    const float nd = norm_dst[n];
    if constexpr (EPI == 0) {
        if (q == 0) {
            const float4 b0 = *(const float4*)&bias[c8];
            const float4 b1 = *(const float4*)&bias[c8 + 4];
            float4 o0, o1;
            o0.x = fmaxf(acc[0] * nd + b0.x, 0.f);
            o0.y = fmaxf(acc[1] * nd + b0.y, 0.f);
            o0.z = fmaxf(acc[2] * nd + b0.z, 0.f);
            o0.w = fmaxf(acc[3] * nd + b0.w, 0.f);
            o1.x = fmaxf(acc[4] * nd + b1.x, 0.f);
            o1.y = fmaxf(acc[5] * nd + b1.y, 0.f);
            o1.z = fmaxf(acc[6] * nd + b1.z, 0.f);
            o1.w = fmaxf(acc[7] * nd + b1.w, 0.f);
            *(float4*)&outv[(size_t)n * F + c8] = o0;
            *(float4*)&outv[(size_t)n * F + c8 + 4] = o1;
        }
    } else {
        const float4 b0 = *(const float4*)&bias[c8];
        const float4 b1 = *(const float4*)&bias[c8 + 4];
        const float4 wa0 = *(const float4*)&Wp[c8];
        const float4 wa1 = *(const float4*)&Wp[c8 + 4];
        const float4 wc0 = *(const float4*)&Wp[F + c8];
        const float4 wc1 = *(const float4*)&Wp[F + c8 + 4];
        const float h0 = acc[0]*nd + b0.x, h1 = acc[1]*nd + b0.y;
        const float h2 = acc[2]*nd + b0.z, h3 = acc[3]*nd + b0.w;
        const float h4 = acc[4]*nd + b1.x, h5 = acc[5]*nd + b1.y;
        const float h6 = acc[6]*nd + b1.z, h7 = acc[7]*nd + b1.w;
        float pa = h0*wa0.x + h1*wa0.y + h2*wa0.z + h3*wa0.w
                 + h4*wa1.x + h5*wa1.y + h6*wa1.z + h7*wa1.w;
        float pc = h0*wc0.x + h1*wc0.y + h2*wc0.z + h3*wc0.w
                 + h4*wc1.x + h5*wc1.y + h6*wc1.z + h7*wc1.w;
        #pragma unroll
        for (int m = 8; m > 0; m >>= 1) {
            pa += __shfl_xor(pa, m);
            pc += __shfl_xor(pc, m);
        }
        if (l == 0) { outa[n] = pa; outc[n] = pc; }
    }
}

// ---------------- edge scores ----------------
__global__ void score_kernel(const float* __restrict__ a, const float* __restrict__ c,
                             const int* __restrict__ src, const int* __restrict__ dst,
                             const float* __restrict__ bp, float* __restrict__ out, int nE) {
    const int e = blockIdx.x * blockDim.x + threadIdx.x;
    if (e < nE) {
        const float z = a[src[e]] + c[dst[e]] + bp[0];
        out[e] = 1.f / (1.f + __expf(-z));
    }
}

extern "C" void kernel_launch(void* const* d_in, const int* in_sizes, int n_in,
                              void* d_out, int out_size, void* d_ws, size_t ws_size,
                              hipStream_t stream) {
    const float* x  = (const float*)d_in[0];
    const float* W1 = (const float*)d_in[1];
    const float* b1 = (const float*)d_in[2];
    const float* W2 = (const float*)d_in[3];
    const float* b2 = (const float*)d_in[4];
    const float* Wp = (const float*)d_in[5];
    const float* bp = (const float*)d_in[6];
    const int*   src = (const int*)d_in[7];
    const int*   dst = (const int*)d_in[8];
    float* out = (float*)d_out;

    float* ws       = (float*)d_ws;
    float* norm_src = ws;                       // NPAD
    float* norm_dst = ws + NPAD;                // NPAD
    float* bufA     = ws + 2 * NPAD;            // NPAD: deg_out, later a[]
    float* bufC     = ws + 3 * NPAD;            // NPAD: deg_in, later c[]
    int*   offsets  = (int*)(ws + 4 * NPAD);    // NPAD + 4
    int*   cursor   = offsets + NPAD + 4;       // NPAD
    int*   sorted   = cursor + NPAD;            // NE
    int*   bsums    = sorted + NE;              // 128
    unsigned short* hs_bf = (unsigned short*)(bsums + 128);   // NN*F bf16 (25.6 MB)
    float* agg      = (float*)(hs_bf + (size_t)NN * F);       // NN*F fp32 (51.2 MB)

    // degrees -> norms
    hipMemsetAsync(bufA, 0, 2 * NPAD * sizeof(float), stream);
    deg_kernel<<<(NE + 255) / 256, 256, 0, stream>>>(src, dst, (int*)bufA, (int*)bufC, NE);
    norm_kernel<<<(NN + 255) / 256, 256, 0, stream>>>((int*)bufA, (int*)bufC, norm_src, norm_dst, NN);

    // CSR scan (counting sort by dst)
    scan_sums<<<SCAN_BLOCKS, 256, 0, stream>>>((const int*)bufC, bsums);
    scan_top<<<1, 64, 0, stream>>>(bsums);
    scan_final<<<SCAN_BLOCKS, 256, 0, stream>>>((const int*)bufC, bsums, offsets, cursor);

    // layer 1 GEMM overlapped with CSR fill
    gemm1_fill_kernel<<<768, 256, 0, stream>>>(x, W1, norm_src, hs_bf, src, dst, cursor, sorted);

    // gather1: agg = relu(sum(hs_bf[src]) * norm_dst + b1)  (fp32 out)
    gather_kernel<0><<<NN * 64 / 256, 256, 0, stream>>>(hs_bf, sorted, offsets, norm_dst, b1, nullptr,
                                                        agg, nullptr, nullptr, NN);

    // layer 2 GEMM: hs_bf = bf16((agg @ W2) * norm_src)
    gemm_kernel<<<512, 256, 0, stream>>>(agg, W2, norm_src, hs_bf);

    // gather2 fused with link-head partials: a[n], c[n]
    gather_kernel<1><<<NN * 64 / 256, 256, 0, stream>>>(hs_bf, sorted, offsets, norm_dst, b2, Wp,
                                                        nullptr, bufA, bufC, NN);

    // edge scores
    score_kernel<<<(NE + 255) / 256, 256, 0, stream>>>(bufA, bufC, src, dst, bp, out, NE);
}

// Round 5
// 534.723 us; speedup vs baseline: 10.7597x; 1.0779x over previous
//
#include <hip/hip_runtime.h>
#include <cstdint>
#include <cstddef>

#define NN 100000
#define NE 1600000
#define F  128
#define NPAD 100352          // 98 * 1024
#define SCAN_BLOCKS 98       // NPAD / 1024

// bf16 storage helpers (RNE, finite values only)
__device__ __forceinline__ unsigned short f2bf(float f) {
    unsigned u = __float_as_uint(f);
    unsigned r = (u + 0x7fffu + ((u >> 16) & 1u)) >> 16;
    return (unsigned short)r;
}
__device__ __forceinline__ void acc_bf8(const uint4 v, float* acc) {
    acc[0] += __uint_as_float(v.x << 16);
    acc[1] += __uint_as_float(v.x & 0xffff0000u);
    acc[2] += __uint_as_float(v.y << 16);
    acc[3] += __uint_as_float(v.y & 0xffff0000u);
    acc[4] += __uint_as_float(v.z << 16);
    acc[5] += __uint_as_float(v.z & 0xffff0000u);
    acc[6] += __uint_as_float(v.w << 16);
    acc[7] += __uint_as_float(v.w & 0xffff0000u);
}

// ---------------- degree ----------------
__global__ void deg_kernel(const int* __restrict__ src, const int* __restrict__ dst,
                           int* __restrict__ deg_out, int* __restrict__ deg_in, int nE) {
    int e = blockIdx.x * blockDim.x + threadIdx.x;
    if (e < nE) {
        atomicAdd(&deg_out[src[e]], 1);
        atomicAdd(&deg_in[dst[e]], 1);
    }
}

__global__ void norm_kernel(const int* __restrict__ deg_out, const int* __restrict__ deg_in,
                            float* __restrict__ norm_src, float* __restrict__ norm_dst, int nN) {
    int n = blockIdx.x * blockDim.x + threadIdx.x;
    if (n < nN) {
        norm_src[n] = rsqrtf((float)max(deg_out[n], 1));
        norm_dst[n] = rsqrtf((float)max(deg_in[n], 1));
    }
}

// ---------------- head constant: cc = b2.Wp_a + b2.Wp_c + bp ----------------
__global__ void head_const_kernel(const float* __restrict__ b2, const float* __restrict__ Wp,
                                  const float* __restrict__ bp, float* __restrict__ consts) {
    const int l = threadIdx.x;           // 64 lanes
    const float2 bb = *(const float2*)&b2[2 * l];
    const float2 wa = *(const float2*)&Wp[2 * l];
    const float2 wc = *(const float2*)&Wp[F + 2 * l];
    float s = bb.x * (wa.x + wc.x) + bb.y * (wa.y + wc.y);
    #pragma unroll
    for (int m = 32; m > 0; m >>= 1) s += __shfl_xor(s, m);
    if (l == 0) consts[0] = s + bp[0];
}

// ---------------- counting-sort scan (deg_in -> exclusive offsets) ----------------
__global__ void scan_sums(const int* __restrict__ deg, int* __restrict__ bsums) {
    const int b = blockIdx.x, tid = threadIdx.x;
    int s = 0;
    #pragma unroll
    for (int k = 0; k < 4; ++k) {
        int g = b * 1024 + tid * 4 + k;
        s += (g < NN) ? deg[g] : 0;
    }
    __shared__ int sc[256];
    sc[tid] = s; __syncthreads();
    for (int off = 128; off > 0; off >>= 1) {
        if (tid < off) sc[tid] += sc[tid + off];
        __syncthreads();
    }
    if (tid == 0) bsums[b] = sc[0];
}

__global__ void scan_top(int* __restrict__ bsums) {
    if (threadIdx.x == 0 && blockIdx.x == 0) {
        int run = 0;
        for (int i = 0; i < SCAN_BLOCKS; ++i) { int v = bsums[i]; bsums[i] = run; run += v; }
    }
}

__global__ void scan_final(const int* __restrict__ deg, const int* __restrict__ bsums,
                           int* __restrict__ offsets, int* __restrict__ cursor) {
    const int b = blockIdx.x, tid = threadIdx.x;
    int d[4], s = 0;
    #pragma unroll
    for (int k = 0; k < 4; ++k) {
        int g = b * 1024 + tid * 4 + k;
        d[k] = (g < NN) ? deg[g] : 0;
        s += d[k];
    }
    __shared__ int sc[256];
    sc[tid] = s; __syncthreads();
    for (int off = 1; off < 256; off <<= 1) {
        int v = (tid >= off) ? sc[tid - off] : 0;
        __syncthreads();
        sc[tid] += v;
        __syncthreads();
    }
    int excl = bsums[b] + sc[tid] - s;
    #pragma unroll
    for (int k = 0; k < 4; ++k) {
        int g = b * 1024 + tid * 4 + k;
        if (g <= NN) { offsets[g] = excl; if (g < NN) cursor[g] = excl; }
        excl += d[k];
    }
}

// ---------------- fused gemm1 + fill ----------------
// blockIdx%3==2 -> fill role (256 blocks, 4 independent atomics in flight)
// else          -> gemm role (512 blocks): hs_bf[n][:] = bf16((x[n][:] @ W1) * norm_src[n])
__global__ __launch_bounds__(256, 2)
void gemm1_fill_kernel(const float* __restrict__ in, const float* __restrict__ W,
                       const float* __restrict__ norm_src, unsigned short* __restrict__ out_bf,
                       const int* __restrict__ src, const int* __restrict__ dst,
                       int* __restrict__ cursor, int* __restrict__ sorted_src) {
    __shared__ __align__(16) float Ws[F * F];      // 64 KB [k][c]
    __shared__ __align__(16) float xs[32][F];      // 16 KB

    const int g = blockIdx.x;
    const int r3 = g % 3;
    const int tid = threadIdx.x;

    if (r3 == 2) {                                  // ---- fill role
        const int S = 256 * 256;                    // 65536 threads
        const int base = (g / 3) * 256 + tid;
        int e = base;
        for (; e + 3 * S < NE; e += 4 * S) {
            const int d0 = dst[e], d1 = dst[e + S], d2 = dst[e + 2 * S], d3 = dst[e + 3 * S];
            const int s0 = src[e], s1 = src[e + S], s2 = src[e + 2 * S], s3 = src[e + 3 * S];
            const int p0 = atomicAdd(&cursor[d0], 1);
            const int p1 = atomicAdd(&cursor[d1], 1);
            const int p2 = atomicAdd(&cursor[d2], 1);
            const int p3 = atomicAdd(&cursor[d3], 1);
            __builtin_nontemporal_store(s0, &sorted_src[p0]);
            __builtin_nontemporal_store(s1, &sorted_src[p1]);
            __builtin_nontemporal_store(s2, &sorted_src[p2]);
            __builtin_nontemporal_store(s3, &sorted_src[p3]);
        }
        for (; e < NE; e += S) {
            const int p = atomicAdd(&cursor[dst[e]], 1);
            __builtin_nontemporal_store(src[e], &sorted_src[p]);
        }
        return;
    }

    const int gid = (g / 3) * 2 + r3;               // ---- gemm role (512 blocks)
    for (int i = tid * 4; i < F * F; i += 256 * 4) {
        *(float4*)&Ws[i] = *(const float4*)&W[i];
    }

    const int l  = tid & 63;
    const int w  = tid >> 6;
    const int cg = l & 31;
    const int rg = l >> 5;
    const int c0 = cg * 4;

    const int nTiles = NN / 32;                     // 3125
    for (int tile = gid; tile < nTiles; tile += 512) {
        const int row0 = tile * 32;
        __syncthreads();
        for (int i = tid; i < 32 * 32; i += 256) {
            const int r  = i >> 5;
            const int k4 = (i & 31) * 4;
            *(float4*)&xs[r][k4] = *(const float4*)&in[(size_t)(row0 + r) * F + k4];
        }
        __syncthreads();

        const int r0 = 8 * w + 4 * rg;
        float4 a0 = {0,0,0,0}, a1 = {0,0,0,0}, a2 = {0,0,0,0}, a3 = {0,0,0,0};
        #pragma unroll 8
        for (int k = 0; k < F; ++k) {
            const float4 wv = *(const float4*)&Ws[k * F + c0];
            const float x0 = xs[r0 + 0][k];
            const float x1 = xs[r0 + 1][k];
            const float x2 = xs[r0 + 2][k];
            const float x3 = xs[r0 + 3][k];
            a0.x += x0 * wv.x; a0.y += x0 * wv.y; a0.z += x0 * wv.z; a0.w += x0 * wv.w;
            a1.x += x1 * wv.x; a1.y += x1 * wv.y; a1.z += x1 * wv.z; a1.w += x1 * wv.w;
            a2.x += x2 * wv.x; a2.y += x2 * wv.y; a2.z += x2 * wv.z; a2.w += x2 * wv.w;
            a3.x += x3 * wv.x; a3.y += x3 * wv.y; a3.z += x3 * wv.z; a3.w += x3 * wv.w;
        }
        const float ns0 = norm_src[row0 + r0 + 0];
        const float ns1 = norm_src[row0 + r0 + 1];
        const float ns2 = norm_src[row0 + r0 + 2];
        const float ns3 = norm_src[row0 + r0 + 3];
        ushort4 o;
        o.x = f2bf(a0.x*ns0); o.y = f2bf(a0.y*ns0); o.z = f2bf(a0.z*ns0); o.w = f2bf(a0.w*ns0);
        *(ushort4*)&out_bf[(size_t)(row0 + r0 + 0) * F + c0] = o;
        o.x = f2bf(a1.x*ns1); o.y = f2bf(a1.y*ns1); o.z = f2bf(a1.z*ns1); o.w = f2bf(a1.w*ns1);
        *(ushort4*)&out_bf[(size_t)(row0 + r0 + 1) * F + c0] = o;
        o.x = f2bf(a2.x*ns2); o.y = f2bf(a2.y*ns2); o.z = f2bf(a2.z*ns2); o.w = f2bf(a2.w*ns2);
        *(ushort4*)&out_bf[(size_t)(row0 + r0 + 2) * F + c0] = o;
        o.x = f2bf(a3.x*ns3); o.y = f2bf(a3.y*ns3); o.z = f2bf(a3.z*ns3); o.w = f2bf(a3.w*ns3);
        *(ushort4*)&out_bf[(size_t)(row0 + r0 + 3) * F + c0] = o;
    }
}

// ---------------- gemm2 + head projection ----------------
// hs2_row = (agg[n][:] @ W2) * norm_src[n]  (fp32, never materialized)
// uw[n] = (hs2_row . Wp[:128], hs2_row . Wp[128:])
__global__ __launch_bounds__(256, 2)
void gemm2_uw_kernel(const float* __restrict__ in, const float* __restrict__ W,
                     const float* __restrict__ norm_src, const float* __restrict__ Wp,
                     float2* __restrict__ uw) {
    __shared__ __align__(16) float Ws[F * F];
    __shared__ __align__(16) float xs[32][F];

    const int tid = threadIdx.x;
    for (int i = tid * 4; i < F * F; i += 256 * 4) {
        *(float4*)&Ws[i] = *(const float4*)&W[i];
    }

    const int l  = tid & 63;
    const int w  = tid >> 6;
    const int cg = l & 31;
    const int rg = l >> 5;
    const int c0 = cg * 4;

    const float4 wa = *(const float4*)&Wp[c0];       // head weights for our 4 cols
    const float4 wc = *(const float4*)&Wp[F + c0];

    const int nTiles = NN / 32;
    for (int tile = blockIdx.x; tile < nTiles; tile += gridDim.x) {
        const int row0 = tile * 32;
        __syncthreads();
        for (int i = tid; i < 32 * 32; i += 256) {
            const int r  = i >> 5;
            const int k4 = (i & 31) * 4;
            *(float4*)&xs[r][k4] = *(const float4*)&in[(size_t)(row0 + r) * F + k4];
        }
        __syncthreads();

        const int r0 = 8 * w + 4 * rg;
        float4 a0 = {0,0,0,0}, a1 = {0,0,0,0}, a2 = {0,0,0,0}, a3 = {0,0,0,0};
        #pragma unroll 8
        for (int k = 0; k < F; ++k) {
            const float4 wv = *(const float4*)&Ws[k * F + c0];
            const float x0 = xs[r0 + 0][k];
            const float x1 = xs[r0 + 1][k];
            const float x2 = xs[r0 + 2][k];
            const float x3 = xs[r0 + 3][k];
            a0.x += x0 * wv.x; a0.y += x0 * wv.y; a0.z += x0 * wv.z; a0.w += x0 * wv.w;
            a1.x += x1 * wv.x; a1.y += x1 * wv.y; a1.z += x1 * wv.z; a1.w += x1 * wv.w;
            a2.x += x2 * wv.x; a2.y += x2 * wv.y; a2.z += x2 * wv.z; a2.w += x2 * wv.w;
            a3.x += x3 * wv.x; a3.y += x3 * wv.y; a3.z += x3 * wv.z; a3.w += x3 * wv.w;
        }
        // epilogue: per-row scale by norm_src, then dot with Wp_a / Wp_c and
        // reduce across the 32 lanes (cg 0..31) holding this row.
        #pragma unroll
        for (int i = 0; i < 4; ++i) {
            const float4 av = (i == 0) ? a0 : (i == 1) ? a1 : (i == 2) ? a2 : a3;
            const int row = row0 + r0 + i;
            const float ns = norm_src[row];
            float pa = (av.x * wa.x + av.y * wa.y + av.z * wa.z + av.w * wa.w) * ns;
            float pc = (av.x * wc.x + av.y * wc.y + av.z * wc.z + av.w * wc.w) * ns;
            #pragma unroll
            for (int m = 1; m <= 16; m <<= 1) {
                pa += __shfl_xor(pa, m);
                pc += __shfl_xor(pc, m);
            }
            if (cg == 0) uw[row] = make_float2(pa, pc);
        }
    }
}

// ---------------- gather1: agg[n][:] = relu(sum(hs_bf[src]) * norm_dst + b1) ----------------
// one wave per node; 16 lanes per edge (8 bf16 cols each) -> 4 edges in flight, 8 with unroll
__global__ __launch_bounds__(256)
void gather_kernel(const unsigned short* __restrict__ hs, const int* __restrict__ sorted_src,
                   const int* __restrict__ offsets, const float* __restrict__ norm_dst,
                   const float* __restrict__ bias, float* __restrict__ outv, int nN) {
    const int gid = blockIdx.x * blockDim.x + threadIdx.x;
    const int n = gid >> 6;
    if (n >= nN) return;
    const int l  = threadIdx.x & 63;
    const int q  = l >> 4;                  // quarter: which edge of the 4-group
    const int c8 = (l & 15) * 8;            // 8 bf16 cols per lane
    const int beg = offsets[n];
    const int end = offsets[n + 1];

    float acc[8] = {0.f, 0.f, 0.f, 0.f, 0.f, 0.f, 0.f, 0.f};
    int j = beg;
    for (; j + 8 <= end; j += 8) {          // 8 edges in flight per wave
        const int s0 = sorted_src[j + q];
        const int s1 = sorted_src[j + 4 + q];
        const uint4 v0 = *(const uint4*)&hs[(size_t)s0 * F + c8];
        const uint4 v1 = *(const uint4*)&hs[(size_t)s1 * F + c8];
        acc_bf8(v0, acc);
        acc_bf8(v1, acc);
    }
    for (; j + 4 <= end; j += 4) {
        const int s = sorted_src[j + q];
        const uint4 v = *(const uint4*)&hs[(size_t)s * F + c8];
        acc_bf8(v, acc);
    }
    if (j + q < end) {
        const int s = sorted_src[j + q];
        const uint4 v = *(const uint4*)&hs[(size_t)s * F + c8];
        acc_bf8(v, acc);
    }
    #pragma unroll
    for (int k = 0; k < 8; ++k) {
        acc[k] += __shfl_xor(acc[k], 16);
        acc[k] += __shfl_xor(acc[k], 32);
    }

    if (q == 0) {
        const float nd = norm_dst[n];
        const float4 b0 = *(const float4*)&bias[c8];
        const float4 b1v = *(const float4*)&bias[c8 + 4];
        float4 o0, o1;
        o0.x = fmaxf(acc[0] * nd + b0.x, 0.f);
        o0.y = fmaxf(acc[1] * nd + b0.y, 0.f);
        o0.z = fmaxf(acc[2] * nd + b0.z, 0.f);
        o0.w = fmaxf(acc[3] * nd + b0.w, 0.f);
        o1.x = fmaxf(acc[4] * nd + b1v.x, 0.f);
        o1.y = fmaxf(acc[5] * nd + b1v.y, 0.f);
        o1.z = fmaxf(acc[6] * nd + b1v.z, 0.f);
        o1.w = fmaxf(acc[7] * nd + b1v.w, 0.f);
        *(float4*)&outv[(size_t)n * F + c8] = o0;
        *(float4*)&outv[(size_t)n * F + c8 + 4] = o1;
    }
}

// ---------------- layer-2 scalar aggregation: A[n]=nd*sum(u[src]), C[n]=nd*sum(w[src]) ----------------
__global__ void ac_kernel(const float2* __restrict__ uw, const int* __restrict__ sorted_src,
                          const int* __restrict__ offsets, const float* __restrict__ norm_dst,
                          float* __restrict__ A, float* __restrict__ C, int nN) {
    const int n = blockIdx.x * blockDim.x + threadIdx.x;
    if (n >= nN) return;
    const int beg = offsets[n];
    const int end = offsets[n + 1];
    float su = 0.f, sw = 0.f;
    int j = beg;
    for (; j + 2 <= end; j += 2) {
        const int s0 = sorted_src[j];
        const int s1 = sorted_src[j + 1];
        const float2 t0 = uw[s0];
        const float2 t1 = uw[s1];
        su += t0.x + t1.x;
        sw += t0.y + t1.y;
    }
    if (j < end) {
        const float2 t = uw[sorted_src[j]];
        su += t.x;
        sw += t.y;
    }
    const float nd = norm_dst[n];
    A[n] = nd * su;
    C[n] = nd * sw;
}

// ---------------- edge scores ----------------
__global__ void score_kernel(const float* __restrict__ A, const float* __restrict__ C,
                             const int* __restrict__ src, const int* __restrict__ dst,
                             const float* __restrict__ consts, float* __restrict__ out, int nE) {
    const int e = blockIdx.x * blockDim.x + threadIdx.x;
    if (e < nE) {
        const float z = A[src[e]] + C[dst[e]] + consts[0];
        out[e] = 1.f / (1.f + __expf(-z));
    }
}

extern "C" void kernel_launch(void* const* d_in, const int* in_sizes, int n_in,
                              void* d_out, int out_size, void* d_ws, size_t ws_size,
                              hipStream_t stream) {
    const float* x  = (const float*)d_in[0];
    const float* W1 = (const float*)d_in[1];
    const float* b1 = (const float*)d_in[2];
    const float* W2 = (const float*)d_in[3];
    const float* b2 = (const float*)d_in[4];
    const float* Wp = (const float*)d_in[5];
    const float* bp = (const float*)d_in[6];
    const int*   src = (const int*)d_in[7];
    const int*   dst = (const int*)d_in[8];
    float* out = (float*)d_out;

    float* ws       = (float*)d_ws;
    float* norm_src = ws;                       // NPAD
    float* norm_dst = ws + NPAD;                // NPAD
    float* bufA     = ws + 2 * NPAD;            // NPAD: deg_out, later A[]
    float* bufC     = ws + 3 * NPAD;            // NPAD: deg_in, later C[]
    int*   offsets  = (int*)(ws + 4 * NPAD);    // NPAD + 4
    int*   cursor   = offsets + NPAD + 4;       // NPAD
    int*   sorted   = cursor + NPAD;            // NE
    int*   bsums    = sorted + NE;              // 126
    float* consts   = (float*)(bsums + 126);    // 2
    unsigned short* hs_bf = (unsigned short*)(consts + 2);    // NN*F bf16 (25.6 MB)
    float* agg      = (float*)(hs_bf + (size_t)NN * F);       // NN*F fp32 (51.2 MB)
    float2* uw      = (float2*)(agg + (size_t)NN * F);        // NN float2 (0.8 MB)

    // degrees -> norms
    hipMemsetAsync(bufA, 0, 2 * NPAD * sizeof(float), stream);
    deg_kernel<<<(NE + 255) / 256, 256, 0, stream>>>(src, dst, (int*)bufA, (int*)bufC, NE);
    norm_kernel<<<(NN + 255) / 256, 256, 0, stream>>>((int*)bufA, (int*)bufC, norm_src, norm_dst, NN);

    // CSR scan (counting sort by dst) + head constant
    scan_sums<<<SCAN_BLOCKS, 256, 0, stream>>>((const int*)bufC, bsums);
    scan_top<<<1, 64, 0, stream>>>(bsums);
    scan_final<<<SCAN_BLOCKS, 256, 0, stream>>>((const int*)bufC, bsums, offsets, cursor);
    head_const_kernel<<<1, 64, 0, stream>>>(b2, Wp, bp, consts);

    // layer 1 GEMM overlapped with CSR fill
    gemm1_fill_kernel<<<768, 256, 0, stream>>>(x, W1, norm_src, hs_bf, src, dst, cursor, sorted);

    // gather1: agg = relu(sum(hs_bf[src]) * norm_dst + b1)  (fp32 out)
    gather_kernel<<<NN * 64 / 256, 256, 0, stream>>>(hs_bf, sorted, offsets, norm_dst, b1, agg, NN);

    // layer 2 GEMM fused with head projection: uw[n] = (hs2_n . Wp_a, hs2_n . Wp_c)
    gemm2_uw_kernel<<<512, 256, 0, stream>>>(agg, W2, norm_src, Wp, uw);

    // layer-2 aggregation collapsed to scalar sums
    ac_kernel<<<(NN + 255) / 256, 256, 0, stream>>>(uw, sorted, offsets, norm_dst, bufA, bufC, NN);

    // edge scores
    score_kernel<<<(NE + 255) / 256, 256, 0, stream>>>(bufA, bufC, src, dst, consts, out, NE);
}